// Round 5
// baseline (212.246 us; speedup 1.0000x reference)
//
#include <hip/hip_runtime.h>
#include <hip/hip_bf16.h>
#include <stdint.h>

#define M_DIM 8192
#define N_DIM 8192
#define D_DIM 512          // elements; 512 bytes per row in fp8
#define BM 128
#define BN 128
#define BKB 128            // K-bytes per MFMA step
#define KITERS (D_DIM / BKB)   // 4

typedef int v8i __attribute__((ext_vector_type(8)));
typedef float f32x4 __attribute__((ext_vector_type(4)));

// 256 threads = 4 waves; one wave per row: fp32 -> fp8(e4m3) + squared norm.
// Blocks 0..31 also initialize out[] = bias.
__global__ __launch_bounds__(256) void prep_kernel(
    const float* __restrict__ x, const float* __restrict__ xt,
    char* __restrict__ xb, char* __restrict__ xtb,
    float* __restrict__ xx, float* __restrict__ yy,
    float* __restrict__ out, const float* __restrict__ bias) {
  if (blockIdx.x < 32) out[blockIdx.x * 256 + threadIdx.x] = bias[0];
  const int wid = threadIdx.x >> 6;
  const int lane = threadIdx.x & 63;
  int row = blockIdx.x * 4 + wid;
  const float* src;
  char* dst;
  float* nrm;
  if (row < M_DIM) {
    src = x + (size_t)row * D_DIM;
    dst = xb + (size_t)row * D_DIM;
    nrm = xx + row;
  } else {
    int r = row - M_DIM;
    src = xt + (size_t)r * D_DIM;
    dst = xtb + (size_t)r * D_DIM;
    nrm = yy + r;
  }
  const float4* s4 = (const float4*)src;
  float4 a = s4[lane * 2];
  float4 b = s4[lane * 2 + 1];
  float nv = a.x * a.x + a.y * a.y + a.z * a.z + a.w * a.w +
             b.x * b.x + b.y * b.y + b.z * b.z + b.w * b.w;
  int w0 = __builtin_amdgcn_cvt_pk_fp8_f32(a.x, a.y, 0, false);
  w0 = __builtin_amdgcn_cvt_pk_fp8_f32(a.z, a.w, w0, true);
  int w1 = __builtin_amdgcn_cvt_pk_fp8_f32(b.x, b.y, 0, false);
  w1 = __builtin_amdgcn_cvt_pk_fp8_f32(b.z, b.w, w1, true);
  int2 pk; pk.x = w0; pk.y = w1;
  ((int2*)dst)[lane] = pk;
#pragma unroll
  for (int off = 32; off; off >>= 1) nv += __shfl_xor(nv, off, 64);
  if (lane == 0) *nrm = nv;
}

// 128x128 tile, MX-fp8 K=128 MFMA, 4 waves (2x2), 4 K-iterations.
// NO operand LDS: fragments loaded directly from global (L1/L2-resident via
// XCD-swizzled 8x8 tile clusters). No K-loop barriers, no staging drains,
// compiler free to pipeline 64 loads across 64 MFMAs.
// Operand-swapped: A-op = y-frags (n), B-op = x-frags (m) -> C: m=lane&15,
// n=(lane>>4)*4+reg; N-reduction mostly in-register.
__global__ __launch_bounds__(256, 2) void rbf_gemm(
    const char* __restrict__ A,  // [M][512] fp8 bytes
    const char* __restrict__ B,  // [N][512] fp8 bytes
    const float* __restrict__ xx, const float* __restrict__ yy,
    const float* __restrict__ w, const float* __restrict__ gamma,
    float* __restrict__ out) {
  __shared__ float rowsum[BM];

  const int tid = threadIdx.x;
  const int lane = tid & 63;
  const int wid = tid >> 6;
  const int wm = wid >> 1;  // M half
  const int wn = wid & 1;   // N half

  // XCD-aware swizzle: 8x8 tile clusters per XCD (L2-resident A+B region).
  const int b = blockIdx.x;
  const int g = b >> 9;
  const int xcd = b & 7;
  const int p = (b >> 3) & 63;
  const int bm = g * 8 + (p >> 3);
  const int bn = xcd * 8 + (p & 7);

  if (tid < BM) rowsum[tid] = 0.0f;
  __syncthreads();

  const int frow = lane & 15;  // non-K index within 16
  const int fk8 = lane >> 4;   // which 32-byte K-chunk (0..3)
  const int sc1 = 127;         // e8m0 scale byte 127 -> x1.0

  // Per-lane fragment base pointers (k-offset fk8*32 folded in).
  const char* bp[4];
  const char* ap[4];
#pragma unroll
  for (int i = 0; i < 4; i++)
    bp[i] = B + (size_t)(bn * BN + wn * 64 + i * 16 + frow) * D_DIM + fk8 * 32;
#pragma unroll
  for (int j = 0; j < 4; j++)
    ap[j] = A + (size_t)(bm * BM + wm * 64 + j * 16 + frow) * D_DIM + fk8 * 32;

  f32x4 acc[4][4];  // [i = n-tile][j = m-tile]
  const f32x4 zero = {0.f, 0.f, 0.f, 0.f};
#pragma unroll
  for (int i = 0; i < 4; i++)
#pragma unroll
    for (int j = 0; j < 4; j++) acc[i][j] = zero;

#pragma unroll
  for (int kt = 0; kt < KITERS; ++kt) {
    const int k0 = kt * BKB;
    v8i an[4], am[4];
#pragma unroll
    for (int i = 0; i < 4; i++) {
      union { int4 q[2]; v8i v; } u;
      u.q[0] = *(const int4*)(bp[i] + k0);
      u.q[1] = *(const int4*)(bp[i] + k0 + 16);
      an[i] = u.v;
    }
#pragma unroll
    for (int j = 0; j < 4; j++) {
      union { int4 q[2]; v8i v; } u;
      u.q[0] = *(const int4*)(ap[j] + k0);
      u.q[1] = *(const int4*)(ap[j] + k0 + 16);
      am[j] = u.v;
    }
#pragma unroll
    for (int i = 0; i < 4; i++)
#pragma unroll
      for (int j = 0; j < 4; j++)
        acc[i][j] = __builtin_amdgcn_mfma_scale_f32_16x16x128_f8f6f4(
            an[i], am[j], acc[i][j], 0, 0, /*opsel_a*/ 0, sc1, /*opsel_b*/ 0,
            sc1);
  }

  // Epilogue. C layout (swapped operands): m = lane&15, n = (lane>>4)*4 + reg.
  const float g2 = gamma[0];
  float xv[4];
#pragma unroll
  for (int j = 0; j < 4; j++)
    xv[j] = xx[bm * BM + wm * 64 + j * 16 + frow];
  float s[4] = {0.f, 0.f, 0.f, 0.f};
#pragma unroll
  for (int i = 0; i < 4; i++) {
#pragma unroll
    for (int r = 0; r < 4; r++) {
      int n = bn * BN + wn * 64 + i * 16 + fk8 * 4 + r;
      float yv = yy[n], wv = w[n];
#pragma unroll
      for (int j = 0; j < 4; j++) {
        float v = acc[i][j][r];
        float sq = fmaxf(xv[j] + yv - 2.0f * v, 0.0f);
        s[j] += wv * __expf(-g2 * sq);
      }
    }
  }
#pragma unroll
  for (int j = 0; j < 4; j++) {  // reduce over fk8 groups (lanes 16,32 apart)
    s[j] += __shfl_xor(s[j], 16, 64);
    s[j] += __shfl_xor(s[j], 32, 64);
  }
  if (lane < 16) {
#pragma unroll
    for (int j = 0; j < 4; j++)
      atomicAdd(&rowsum[wm * 64 + j * 16 + lane], s[j]);
  }
  __syncthreads();
  if (tid < BM) atomicAdd(&out[bm * BM + tid], rowsum[tid]);
}

extern "C" void kernel_launch(void* const* d_in, const int* in_sizes, int n_in,
                              void* d_out, int out_size, void* d_ws, size_t ws_size,
                              hipStream_t stream) {
  const float* x = (const float*)d_in[0];       // [8192,512]
  const float* xt = (const float*)d_in[1];      // [8192,512]
  const float* gamma = (const float*)d_in[2];   // [1]
  const float* weight = (const float*)d_in[3];  // [8192,1]
  const float* bias = (const float*)d_in[4];    // [1]
  float* out = (float*)d_out;                   // [8192]

  char* ws = (char*)d_ws;
  char* xb = ws;                                             // 4 MB fp8
  char* xtb = ws + (size_t)4 * 1024 * 1024;                  // 4 MB fp8
  float* xx = (float*)(ws + (size_t)8 * 1024 * 1024);        // 32 KB
  float* yy = (float*)(ws + (size_t)8 * 1024 * 1024 + 32 * 1024);  // 32 KB

  prep_kernel<<<(M_DIM + N_DIM) / 4, 256, 0, stream>>>(x, xt, xb, xtb, xx, yy,
                                                       out, bias);
  rbf_gemm<<<(M_DIM / BM) * (N_DIM / BN), 256, 0, stream>>>(xb, xtb, xx, yy,
                                                            weight, gamma, out);
}

// Round 6
// 134.961 us; speedup vs baseline: 1.5726x; 1.5726x over previous
//
#include <hip/hip_runtime.h>
#include <hip/hip_bf16.h>
#include <stdint.h>

#define M_DIM 8192
#define N_DIM 8192
#define D_DIM 512          // elements; 512 bytes per row in fp8
#define BM 128
#define BN 128
#define BKB 128            // K-bytes per MFMA step
#define KITERS (D_DIM / BKB)   // 4

typedef int v8i __attribute__((ext_vector_type(8)));
typedef float f32x4 __attribute__((ext_vector_type(4)));

__device__ inline void gload_lds16(const void* g, void* l) {
  __builtin_amdgcn_global_load_lds(
      (const __attribute__((address_space(1))) void*)g,
      (__attribute__((address_space(3))) void*)l, 16, 0, 0);
}

// 256 threads = 4 waves; one wave per row: fp32 -> fp8(e4m3) + squared norm.
// Fully coalesced (unit-stride float4 loads, unit-stride int stores).
// Blocks 0..31 also initialize out[] = bias.
__global__ __launch_bounds__(256) void prep_kernel(
    const float* __restrict__ x, const float* __restrict__ xt,
    char* __restrict__ xb, char* __restrict__ xtb,
    float* __restrict__ xx, float* __restrict__ yy,
    float* __restrict__ out, const float* __restrict__ bias) {
  if (blockIdx.x < 32) out[blockIdx.x * 256 + threadIdx.x] = bias[0];
  const int wid = threadIdx.x >> 6;
  const int lane = threadIdx.x & 63;
  int row = blockIdx.x * 4 + wid;
  const float* src;
  char* dst;
  float* nrm;
  if (row < M_DIM) {
    src = x + (size_t)row * D_DIM;
    dst = xb + (size_t)row * D_DIM;
    nrm = xx + row;
  } else {
    int r = row - M_DIM;
    src = xt + (size_t)r * D_DIM;
    dst = xtb + (size_t)r * D_DIM;
    nrm = yy + r;
  }
  const float4* s4 = (const float4*)src;
  float4 a = s4[lane];        // elements 4*lane .. 4*lane+3
  float4 b = s4[lane + 64];   // elements 256+4*lane ..
  float nv = a.x * a.x + a.y * a.y + a.z * a.z + a.w * a.w +
             b.x * b.x + b.y * b.y + b.z * b.z + b.w * b.w;
  int w0 = __builtin_amdgcn_cvt_pk_fp8_f32(a.x, a.y, 0, false);
  w0 = __builtin_amdgcn_cvt_pk_fp8_f32(a.z, a.w, w0, true);
  int w1 = __builtin_amdgcn_cvt_pk_fp8_f32(b.x, b.y, 0, false);
  w1 = __builtin_amdgcn_cvt_pk_fp8_f32(b.z, b.w, w1, true);
  ((int*)dst)[lane] = w0;
  ((int*)dst)[lane + 64] = w1;
#pragma unroll
  for (int off = 32; off; off >>= 1) nv += __shfl_xor(nv, off, 64);
  if (lane == 0) *nrm = nv;
}

// 128x128 tile, MX-fp8 K=128 MFMA, 4 waves (2x2), 4 K-iterations, LDS
// double-buffered: stage(kt+1) issued before compute(kt) so the barrier's
// vmcnt drain overlaps ds_read+MFMA.
// LDS chunk placement: row r stores 16B chunk c at pos rot(c)^(r&7) with
// rot(c)=((c&1)<<2)|(c>>1); fragment reads then hit pos = fk8^(frow&7) and
// (4+fk8)^(frow&7) -- the R2-measured conflict-free patterns.
// Operand-swapped: A-op = y-frags (n), B-op = x-frags (m) -> C: m=lane&15,
// n=(lane>>4)*4+reg; N-reduction mostly in-register.
__global__ __launch_bounds__(256) void rbf_gemm(
    const char* __restrict__ A,  // [M][512] fp8 bytes
    const char* __restrict__ B,  // [N][512] fp8 bytes
    const float* __restrict__ xx, const float* __restrict__ yy,
    const float* __restrict__ w, const float* __restrict__ gamma,
    float* __restrict__ out) {
  __shared__ __align__(16) char As[2][BM * BKB];  // 32 KB
  __shared__ __align__(16) char Bs[2][BN * BKB];  // 32 KB -> 64 KB total

  const int tid = threadIdx.x;
  const int lane = tid & 63;
  const int wid = tid >> 6;
  const int wm = wid >> 1;  // M half
  const int wn = wid & 1;   // N half

  // XCD-aware swizzle: 8x8 tile clusters per XCD (L2-resident A+B region).
  const int b = blockIdx.x;
  const int g = b >> 9;
  const int xcd = b & 7;
  const int p = (b >> 3) & 63;
  const int bm = g * 8 + (p >> 3);
  const int bn = xcd * 8 + (p & 7);

  const size_t a_base = (size_t)bm * BM * D_DIM;
  const size_t b_base = (size_t)bn * BN * D_DIM;

  const int frow = lane & 15;  // non-K index within 16
  const int fk8 = lane >> 4;   // which 32-byte K-chunk (0..3)
  const int sc1 = 127;         // e8m0 scale byte 127 -> x1.0
  const int pq0 = fk8 ^ (frow & 7);        // pos of chunk 2*fk8
  const int pq1 = (4 + fk8) ^ (frow & 7);  // pos of chunk 2*fk8+1

  f32x4 acc[4][4];  // [i = n-tile][j = m-tile]
  const f32x4 zero = {0.f, 0.f, 0.f, 0.f};
#pragma unroll
  for (int i = 0; i < 4; i++)
#pragma unroll
    for (int j = 0; j < 4; j++) acc[i][j] = zero;

  // Stage one K-tile (kt) into buffer buf. Slot (row,pos) <- chunk
  // inv_rot(pos^(row&7)) where inv_rot(cp) = ((cp&3)<<1)|(cp>>2).
  auto stage = [&](int kt, int buf) {
#pragma unroll
    for (int issue = 0; issue < 4; ++issue) {
      int slot = issue * 256 + tid;
      int row = slot >> 3, pos = slot & 7;
      int cp = pos ^ (row & 7);
      int c = ((cp & 3) << 1) | (cp >> 2);
      gload_lds16(A + a_base + (size_t)row * D_DIM + kt * BKB + c * 16,
                  &As[buf][0] + (size_t)(issue * 256 + wid * 64) * 16);
      gload_lds16(B + b_base + (size_t)row * D_DIM + kt * BKB + c * 16,
                  &Bs[buf][0] + (size_t)(issue * 256 + wid * 64) * 16);
    }
  };

  stage(0, 0);
  __syncthreads();  // buffer 0 staged

#pragma unroll
  for (int kt = 0; kt < KITERS; ++kt) {
    if (kt + 1 < KITERS) stage(kt + 1, (kt + 1) & 1);  // prefetch next tile

    const char* as = &As[kt & 1][0];
    const char* bs = &Bs[kt & 1][0];
    v8i an[4], am[4];
#pragma unroll
    for (int i = 0; i < 4; i++) {  // y fragments (N rows)
      int row = wn * 64 + i * 16 + frow;
      union { int4 q[2]; v8i v; } u;
      u.q[0] = *(const int4*)(bs + row * BKB + pq0 * 16);
      u.q[1] = *(const int4*)(bs + row * BKB + pq1 * 16);
      an[i] = u.v;
    }
#pragma unroll
    for (int j = 0; j < 4; j++) {  // x fragments (M rows)
      int row = wm * 64 + j * 16 + frow;
      union { int4 q[2]; v8i v; } u;
      u.q[0] = *(const int4*)(as + row * BKB + pq0 * 16);
      u.q[1] = *(const int4*)(as + row * BKB + pq1 * 16);
      am[j] = u.v;
    }
#pragma unroll
    for (int i = 0; i < 4; i++)
#pragma unroll
      for (int j = 0; j < 4; j++)
        acc[i][j] = __builtin_amdgcn_mfma_scale_f32_16x16x128_f8f6f4(
            an[i], am[j], acc[i][j], 0, 0, /*opsel_a*/ 0, sc1, /*opsel_b*/ 0,
            sc1);
    __syncthreads();  // next buffer staged AND this buffer consumed
  }

  // Epilogue. C layout (swapped operands): m = lane&15, n = (lane>>4)*4 + reg.
  // rowsum aliases the (now dead) As[0] buffer.
  float* rowsum = (float*)&As[0][0];
  if (tid < BM) rowsum[tid] = 0.0f;
  __syncthreads();

  const float g2 = gamma[0];
  float xv[4];
#pragma unroll
  for (int j = 0; j < 4; j++)
    xv[j] = xx[bm * BM + wm * 64 + j * 16 + frow];
  float s[4] = {0.f, 0.f, 0.f, 0.f};
#pragma unroll
  for (int i = 0; i < 4; i++) {
#pragma unroll
    for (int r = 0; r < 4; r++) {
      int n = bn * BN + wn * 64 + i * 16 + fk8 * 4 + r;
      float yv = yy[n], wv = w[n];
#pragma unroll
      for (int j = 0; j < 4; j++) {
        float v = acc[i][j][r];
        float sq = fmaxf(xv[j] + yv - 2.0f * v, 0.0f);
        s[j] += wv * __expf(-g2 * sq);
      }
    }
  }
#pragma unroll
  for (int j = 0; j < 4; j++) {  // reduce over fk8 groups (lanes 16,32 apart)
    s[j] += __shfl_xor(s[j], 16, 64);
    s[j] += __shfl_xor(s[j], 32, 64);
  }
  if (lane < 16) {
#pragma unroll
    for (int j = 0; j < 4; j++)
      atomicAdd(&rowsum[wm * 64 + j * 16 + lane], s[j]);
  }
  __syncthreads();
  if (tid < BM) atomicAdd(&out[bm * BM + tid], rowsum[tid]);
}

extern "C" void kernel_launch(void* const* d_in, const int* in_sizes, int n_in,
                              void* d_out, int out_size, void* d_ws, size_t ws_size,
                              hipStream_t stream) {
  const float* x = (const float*)d_in[0];       // [8192,512]
  const float* xt = (const float*)d_in[1];      // [8192,512]
  const float* gamma = (const float*)d_in[2];   // [1]
  const float* weight = (const float*)d_in[3];  // [8192,1]
  const float* bias = (const float*)d_in[4];    // [1]
  float* out = (float*)d_out;                   // [8192]

  char* ws = (char*)d_ws;
  char* xb = ws;                                             // 4 MB fp8
  char* xtb = ws + (size_t)4 * 1024 * 1024;                  // 4 MB fp8
  float* xx = (float*)(ws + (size_t)8 * 1024 * 1024);        // 32 KB
  float* yy = (float*)(ws + (size_t)8 * 1024 * 1024 + 32 * 1024);  // 32 KB

  prep_kernel<<<(M_DIM + N_DIM) / 4, 256, 0, stream>>>(x, xt, xb, xtb, xx, yy,
                                                       out, bias);
  rbf_gemm<<<(M_DIM / BM) * (N_DIM / BN), 256, 0, stream>>>(xb, xtb, xx, yy,
                                                            weight, gamma, out);
}

// Round 7
// 132.663 us; speedup vs baseline: 1.5999x; 1.0173x over previous
//
#include <hip/hip_runtime.h>
#include <hip/hip_bf16.h>
#include <stdint.h>

#define M_DIM 8192
#define N_DIM 8192
#define D_DIM 512      // elements = bytes per row in fp8
// gemm tile: block = 256(m) x 128(n); wave = 64 m-rows; K fully unrolled.

typedef int v8i __attribute__((ext_vector_type(8)));
typedef float f32x4 __attribute__((ext_vector_type(4)));

__device__ inline void gload_lds16(const void* g, void* l) {
  __builtin_amdgcn_global_load_lds(
      (const __attribute__((address_space(1))) void*)g,
      (__attribute__((address_space(3))) void*)l, 16, 0, 0);
}

// Fragment-panel layout for fp8 workspace:
// row r, k-byte kb  ->  chunk c = r>>4 (16-row chunk), frow = r&15,
//   s = kb>>7, fk8 = (kb>>5)&3, half = (kb>>4)&1, off = kb&15,
//   lane = fk8*16 + frow
//   addr = c*8192 + (s*2+half)*1024 + lane*16 + off
// A wave's MFMA operand load for (chunk c, kstep s) is then two perfectly
// contiguous 1 KB reads (q0 at +0, q1 at +1024) with lane stride 16.

// prep: one block per 16-row chunk. Coalesced fp32 read -> fp8 via LDS
// transpose -> coalesced fragment-panel write. Also per-row norms and
// (blocks 0..31) out[] = bias init.
__global__ __launch_bounds__(256) void prep_kernel(
    const float* __restrict__ x, const float* __restrict__ xt,
    char* __restrict__ xb, char* __restrict__ xtb,
    float* __restrict__ xx, float* __restrict__ yy,
    float* __restrict__ out, const float* __restrict__ bias) {
  __shared__ __align__(16) char lds[16 * 528];  // 16 rows, stride 512+16 pad
  __shared__ float snrm[16];
  const int blk = blockIdx.x;
  const int tid = threadIdx.x;
  if (blk < 32) out[blk * 256 + tid] = bias[0];

  const float* src;
  char* dstbuf;
  float* nrm;
  int cblk;
  if (blk < 512) { src = x; dstbuf = xb; nrm = xx; cblk = blk; }
  else { src = xt; dstbuf = xtb; nrm = yy; cblk = blk - 512; }
  const int r0 = cblk * 16;

  if (tid < 16) snrm[tid] = 0.0f;
  __syncthreads();

  const float4* s4 = (const float4*)(src + (size_t)r0 * D_DIM);
#pragma unroll
  for (int i = 0; i < 8; i++) {
    int fi = i * 256 + tid;            // 0..2047 float4s (16 rows x 128)
    int row = fi >> 7, col4 = fi & 127;
    float4 v = s4[fi];
    atomicAdd(&snrm[row], v.x * v.x + v.y * v.y + v.z * v.z + v.w * v.w);
    int w0 = __builtin_amdgcn_cvt_pk_fp8_f32(v.x, v.y, 0, false);
    w0 = __builtin_amdgcn_cvt_pk_fp8_f32(v.z, v.w, w0, true);
    *(int*)(&lds[row * 528 + col4 * 4]) = w0;
  }
  __syncthreads();

  int4* dst4 = (int4*)(dstbuf + (size_t)cblk * 8192);
#pragma unroll
  for (int i = 0; i < 2; i++) {
    int o = i * 256 + tid;             // 0..511 int4s
    int p = o >> 6, lane = o & 63;
    int s = p >> 1, half = p & 1;
    int frow = lane & 15, fk8 = lane >> 4;
    int4 v = *(const int4*)(&lds[frow * 528 + s * 128 + fk8 * 32 + half * 16]);
    dst4[o] = v;  // coalesced
  }
  if (tid < 16) nrm[r0 + tid] = snrm[tid];
}

// gemm: 2048 blocks (32 bm x 64 bn), 256 threads = 4 waves.
// Wave w owns m-group mg = bm*4+w (64 rows): A panel in 128 VGPRs (am[4][4]).
// B tile (128 n-rows, 64 KB) staged once to LDS. ONE barrier; then 8 n-chunks
// of pure ds_read+MFMA with the exp/weight epilogue fused per chunk into
// running sacc[4]. No K-loop barriers at all.
__global__ __launch_bounds__(256) void rbf_gemm(
    const char* __restrict__ A,  // [128 groups][32 KB] fragment-panel fp8
    const char* __restrict__ B,  // [64 bn][64 KB] fragment-panel fp8
    const float* __restrict__ xx, const float* __restrict__ yy,
    const float* __restrict__ w, const float* __restrict__ gamma,
    float* __restrict__ out) {
  __shared__ __align__(16) char Bs[128 * 512];  // 64 KB

  const int tid = threadIdx.x;
  const int lane = tid & 63;
  const int wid = tid >> 6;
  const int frow = lane & 15;
  const int fk8 = lane >> 4;
  const int sc1 = 127;  // e8m0 scale = x1.0

  // XCD swizzle: per XCD an 8-wide bn stripe crossed with all bm.
  const int b = blockIdx.x;
  const int xcd = b & 7;
  const int loc = b >> 3;        // 0..255
  const int bn = xcd * 8 + (loc & 7);  // 0..63
  const int bm = loc >> 3;             // 0..31

  // Stage B tile: linear 64 KB copy, lane-contiguous.
  const char* bsrc = B + (size_t)bn * 65536;
#pragma unroll
  for (int i = 0; i < 16; i++) {
    int slot = i * 256 + tid;
    gload_lds16(bsrc + (size_t)slot * 16,
                Bs + (size_t)(i * 256 + wid * 64) * 16);
  }

  // A panel -> registers (32 contiguous 1 KB wave-loads).
  const int mg = bm * 4 + wid;  // global 64-row m-group
  const char* asrc = A + (size_t)mg * 32768 + lane * 16;
  v8i am[4][4];
#pragma unroll
  for (int q = 0; q < 4; q++)
#pragma unroll
    for (int s = 0; s < 4; s++) {
      union { int4 h[2]; v8i v; } u;
      u.h[0] = *(const int4*)(asrc + ((q * 4 + s) * 2 + 0) * 1024);
      u.h[1] = *(const int4*)(asrc + ((q * 4 + s) * 2 + 1) * 1024);
      am[q][s] = u.v;
    }

  float xv[4];
#pragma unroll
  for (int q = 0; q < 4; q++) xv[q] = xx[mg * 64 + q * 16 + frow];
  const float g2 = gamma[0];
  float sacc[4] = {0.f, 0.f, 0.f, 0.f};

  __syncthreads();  // B staged (compiler drains vmcnt)

#pragma unroll 2
  for (int nc = 0; nc < 8; nc++) {
    const char* bbase = Bs + nc * 8192 + lane * 16;
    f32x4 acc[4];
    const f32x4 zero = {0.f, 0.f, 0.f, 0.f};
#pragma unroll
    for (int q = 0; q < 4; q++) acc[q] = zero;
#pragma unroll
    for (int s = 0; s < 4; s++) {
      union { int4 h[2]; v8i v; } u;
      u.h[0] = *(const int4*)(bbase + (s * 2 + 0) * 1024);
      u.h[1] = *(const int4*)(bbase + (s * 2 + 1) * 1024);
#pragma unroll
      for (int q = 0; q < 4; q++)
        acc[q] = __builtin_amdgcn_mfma_scale_f32_16x16x128_f8f6f4(
            u.v, am[q][s], acc[q], 0, 0, /*opsel_a*/ 0, sc1, /*opsel_b*/ 0,
            sc1);
    }
    // Fused epilogue for this n-chunk. C layout: m = lane&15 (within chunk q),
    // n = fk8*4 + reg.
    int n0 = bn * 128 + nc * 16 + fk8 * 4;
    float4 yv4 = *(const float4*)(yy + n0);
    float4 wv4 = *(const float4*)(w + n0);
    float yv[4] = {yv4.x, yv4.y, yv4.z, yv4.w};
    float wv[4] = {wv4.x, wv4.y, wv4.z, wv4.w};
#pragma unroll
    for (int q = 0; q < 4; q++) {
#pragma unroll
      for (int r = 0; r < 4; r++) {
        float sq = fmaxf(xv[q] + yv[r] - 2.0f * acc[q][r], 0.0f);
        sacc[q] += wv[r] * __expf(-g2 * sq);
      }
    }
  }

  // Reduce the 16 n-columns held across fk8 groups; one atomic per m-row.
#pragma unroll
  for (int q = 0; q < 4; q++) {
    sacc[q] += __shfl_xor(sacc[q], 16, 64);
    sacc[q] += __shfl_xor(sacc[q], 32, 64);
  }
  if (lane < 16) {
#pragma unroll
    for (int q = 0; q < 4; q++)
      atomicAdd(&out[mg * 64 + q * 16 + lane], sacc[q]);
  }
}

extern "C" void kernel_launch(void* const* d_in, const int* in_sizes, int n_in,
                              void* d_out, int out_size, void* d_ws, size_t ws_size,
                              hipStream_t stream) {
  const float* x = (const float*)d_in[0];       // [8192,512]
  const float* xt = (const float*)d_in[1];      // [8192,512]
  const float* gamma = (const float*)d_in[2];   // [1]
  const float* weight = (const float*)d_in[3];  // [8192,1]
  const float* bias = (const float*)d_in[4];    // [1]
  float* out = (float*)d_out;                   // [8192]

  char* ws = (char*)d_ws;
  char* xb = ws;                                             // 4 MB fp8 panels
  char* xtb = ws + (size_t)4 * 1024 * 1024;                  // 4 MB fp8 panels
  float* xx = (float*)(ws + (size_t)8 * 1024 * 1024);        // 32 KB
  float* yy = (float*)(ws + (size_t)8 * 1024 * 1024 + 32 * 1024);  // 32 KB

  prep_kernel<<<1024, 256, 0, stream>>>(x, xt, xb, xtb, xx, yy, out, bias);
  rbf_gemm<<<2048, 256, 0, stream>>>(xb, xtb, xx, yy, weight, gamma, out);
}

// Round 8
// 114.602 us; speedup vs baseline: 1.8520x; 1.1576x over previous
//
#include <hip/hip_runtime.h>
#include <hip/hip_bf16.h>
#include <stdint.h>

#define M_DIM 8192
#define N_DIM 8192
#define D_DIM 512      // elements = bytes per row in fp8

typedef int v8i __attribute__((ext_vector_type(8)));
typedef float f32x4 __attribute__((ext_vector_type(4)));

__device__ inline void gload_lds16(const void* g, void* l) {
  __builtin_amdgcn_global_load_lds(
      (const __attribute__((address_space(1))) void*)g,
      (__attribute__((address_space(3))) void*)l, 16, 0, 0);
}

// Fragment-panel layout for fp8 workspace:
// row r, k-byte kb -> chunk c = r>>4, frow = r&15, s = kb>>7,
//   fk8 = (kb>>5)&3, half = (kb>>4)&1, off = kb&15, lane = fk8*16+frow
//   addr = c*8192 + (s*2+half)*1024 + lane*16 + off
// MFMA operand load for (chunk, s) = two contiguous 1 KB wave-reads.

// prep: one block per 16-row chunk. Coalesced fp32 read -> fp8 via LDS
// transpose -> coalesced fragment-panel write; shuffle-reduced row norms.
// Blocks 0..31 also init out[] = bias.
__global__ __launch_bounds__(256) void prep_kernel(
    const float* __restrict__ x, const float* __restrict__ xt,
    char* __restrict__ xb, char* __restrict__ xtb,
    float* __restrict__ xx, float* __restrict__ yy,
    float* __restrict__ out, const float* __restrict__ bias) {
  __shared__ __align__(16) char lds[16 * 528];  // 16 rows, stride 512+16 pad
  const int blk = blockIdx.x;
  const int tid = threadIdx.x;
  if (blk < 32) out[blk * 256 + tid] = bias[0];

  const float* src;
  char* dstbuf;
  float* nrm;
  int cblk;
  if (blk < 512) { src = x; dstbuf = xb; nrm = xx; cblk = blk; }
  else { src = xt; dstbuf = xtb; nrm = yy; cblk = blk - 512; }
  const int r0 = cblk * 16;

  // Thread handles 8 float4s of ONE row: row = tid>>4, cols (tid&15)+16*i.
  const int row = tid >> 4, col0 = tid & 15;
  const float4* s4 = (const float4*)(src + (size_t)r0 * D_DIM);
  float nv = 0.f;
#pragma unroll
  for (int i = 0; i < 8; i++) {
    int col4 = col0 + i * 16;
    float4 v = s4[row * 128 + col4];
    nv += v.x * v.x + v.y * v.y + v.z * v.z + v.w * v.w;
    int w0 = __builtin_amdgcn_cvt_pk_fp8_f32(v.x, v.y, 0, false);
    w0 = __builtin_amdgcn_cvt_pk_fp8_f32(v.z, v.w, w0, true);
    *(int*)(&lds[row * 528 + col4 * 4]) = w0;
  }
  // 16 lanes per row are consecutive -> shuffle reduce, one write per row.
  nv += __shfl_xor(nv, 1, 64);
  nv += __shfl_xor(nv, 2, 64);
  nv += __shfl_xor(nv, 4, 64);
  nv += __shfl_xor(nv, 8, 64);
  if (col0 == 0) nrm[r0 + row] = nv;
  __syncthreads();

  int4* dst4 = (int4*)(dstbuf + (size_t)cblk * 8192);
#pragma unroll
  for (int i = 0; i < 2; i++) {
    int o = i * 256 + tid;             // 0..511 int4s
    int p = o >> 6, lane = o & 63;
    int s = p >> 1, half = p & 1;
    int frow = lane & 15, fk8 = lane >> 4;
    int4 v = *(const int4*)(&lds[frow * 528 + s * 128 + fk8 * 32 + half * 16]);
    dst4[o] = v;  // coalesced
  }
}

// gemm: 2048 blocks (32 bm x 64 bn), 512 threads = 8 waves (4 waves/SIMD).
// Wave owns 32 m-rows: A-panel in 64 VGPRs (am[2][4]). B tile (128 n-rows,
// 64 KB) staged once to LDS; ONE barrier; 8 n-chunks of ds_read+MFMA with
// fused exp epilogue (exp2-domain, 3 mandatory VALU/elem, wave-uniform
// underflow skip: u < -149 => exp2(u) == 0.0f exactly).
__global__ __launch_bounds__(512, 4) void rbf_gemm(
    const char* __restrict__ A,  // [512 chunks][8 KB] fragment-panel fp8
    const char* __restrict__ B,  // [64 bn][64 KB] fragment-panel fp8
    const float* __restrict__ xx, const float* __restrict__ yy,
    const float* __restrict__ w, const float* __restrict__ gamma,
    float* __restrict__ out) {
  __shared__ __align__(16) char Bs[128 * 512];  // 64 KB

  const int tid = threadIdx.x;
  const int lane = tid & 63;
  const int wid = tid >> 6;      // 0..7
  const int frow = lane & 15;
  const int fk8 = lane >> 4;
  const int sc1 = 127;           // e8m0 scale = x1.0

  // XCD swizzle: per XCD an 8-wide bn stripe crossed with all bm.
  const int b = blockIdx.x;
  const int xcd = b & 7;
  const int loc = b >> 3;              // 0..255
  const int bn = xcd * 8 + (loc & 7);  // 0..63
  const int bm = loc >> 3;             // 0..31

  // Stage B tile: linear 64 KB copy, lane-contiguous.
  const char* bsrc = B + (size_t)bn * 65536;
#pragma unroll
  for (int i = 0; i < 8; i++) {
    gload_lds16(bsrc + (size_t)(i * 512 + wid * 64 + lane) * 16,
                Bs + (size_t)(i * 512 + wid * 64) * 16);
  }

  // A panel -> registers: wave owns 32 rows = chunks mg*2, mg*2+1.
  const int mg = bm * 8 + wid;   // 0..255 (32-row group)
  v8i am[2][4];
#pragma unroll
  for (int q = 0; q < 2; q++) {
    const char* asrc = A + (size_t)(mg * 2 + q) * 8192 + lane * 16;
#pragma unroll
    for (int s = 0; s < 4; s++) {
      union { int4 h[2]; v8i v; } u;
      u.h[0] = *(const int4*)(asrc + (s * 2 + 0) * 1024);
      u.h[1] = *(const int4*)(asrc + (s * 2 + 1) * 1024);
      am[q][s] = u.v;
    }
  }

  const float g2 = gamma[0];
  const float kk = g2 * 1.44269504088896340736f;  // gamma * log2(e)
  const float k2 = 2.0f * kk;
  float nkx[2];  // -k * ||x_m||^2, hoisted out of the n-loop
#pragma unroll
  for (int q = 0; q < 2; q++) nkx[q] = -kk * xx[mg * 32 + q * 16 + frow];
  float sacc[2] = {0.f, 0.f};

  __syncthreads();  // B staged

#pragma unroll 2
  for (int nc = 0; nc < 8; nc++) {
    const char* bbase = Bs + nc * 8192 + lane * 16;
    f32x4 acc[2];
    const f32x4 zero = {0.f, 0.f, 0.f, 0.f};
    acc[0] = zero; acc[1] = zero;
#pragma unroll
    for (int s = 0; s < 4; s++) {
      union { int4 h[2]; v8i v; } u;
      u.h[0] = *(const int4*)(bbase + (s * 2 + 0) * 1024);
      u.h[1] = *(const int4*)(bbase + (s * 2 + 1) * 1024);
#pragma unroll
      for (int q = 0; q < 2; q++)
        acc[q] = __builtin_amdgcn_mfma_scale_f32_16x16x128_f8f6f4(
            u.v, am[q][s], acc[q], 0, 0, /*opsel_a*/ 0, sc1, /*opsel_b*/ 0,
            sc1);
    }
    // Fused epilogue. C layout: m = lane&15 (chunk q), n = fk8*4 + r.
    // u = -k*(xx+yy-2v) clamped to <=0; contribution = wv * exp2(u).
    int n0 = bn * 128 + nc * 16 + fk8 * 4;
    float4 yv4 = *(const float4*)(yy + n0);
    float4 wv4 = *(const float4*)(w + n0);
    float nky[4] = {-kk * yv4.x, -kk * yv4.y, -kk * yv4.z, -kk * yv4.w};
    float uu[2][4];
    float umax = -1e30f;
#pragma unroll
    for (int q = 0; q < 2; q++)
#pragma unroll
      for (int r = 0; r < 4; r++) {
        float u = fminf(fmaf(k2, acc[q][r], nky[r]) + nkx[q], 0.0f);
        uu[q][r] = u;
        umax = fmaxf(umax, u);
      }
    if (__any(umax > -149.0f)) {  // else every exp2 underflows to exactly 0
      float wv[4] = {wv4.x, wv4.y, wv4.z, wv4.w};
#pragma unroll
      for (int q = 0; q < 2; q++)
#pragma unroll
        for (int r = 0; r < 4; r++)
          sacc[q] = fmaf(wv[r], exp2f(uu[q][r]), sacc[q]);
    }
  }

  // Reduce 16 n-columns across fk8 groups; one atomic per m-row.
#pragma unroll
  for (int q = 0; q < 2; q++) {
    sacc[q] += __shfl_xor(sacc[q], 16, 64);
    sacc[q] += __shfl_xor(sacc[q], 32, 64);
  }
  if (lane < 16) {
#pragma unroll
    for (int q = 0; q < 2; q++)
      atomicAdd(&out[mg * 32 + q * 16 + lane], sacc[q]);
  }
}

extern "C" void kernel_launch(void* const* d_in, const int* in_sizes, int n_in,
                              void* d_out, int out_size, void* d_ws, size_t ws_size,
                              hipStream_t stream) {
  const float* x = (const float*)d_in[0];       // [8192,512]
  const float* xt = (const float*)d_in[1];      // [8192,512]
  const float* gamma = (const float*)d_in[2];   // [1]
  const float* weight = (const float*)d_in[3];  // [8192,1]
  const float* bias = (const float*)d_in[4];    // [1]
  float* out = (float*)d_out;                   // [8192]

  char* ws = (char*)d_ws;
  char* xb = ws;                                             // 4 MB fp8 panels
  char* xtb = ws + (size_t)4 * 1024 * 1024;                  // 4 MB fp8 panels
  float* xx = (float*)(ws + (size_t)8 * 1024 * 1024);        // 32 KB
  float* yy = (float*)(ws + (size_t)8 * 1024 * 1024 + 32 * 1024);  // 32 KB

  prep_kernel<<<1024, 256, 0, stream>>>(x, xt, xb, xtb, xx, yy, out, bias);
  rbf_gemm<<<2048, 512, 0, stream>>>(xb, xtb, xx, yy, weight, gamma, out);
}

// Round 9
// 112.010 us; speedup vs baseline: 1.8949x; 1.0231x over previous
//
#include <hip/hip_runtime.h>
#include <hip/hip_bf16.h>
#include <stdint.h>

#define M_DIM 8192
#define N_DIM 8192
#define D_DIM 512      // elements = bytes per row in fp8

typedef int v8i __attribute__((ext_vector_type(8)));
typedef float f32x4 __attribute__((ext_vector_type(4)));

__device__ inline void gload_lds16(const void* g, void* l) {
  __builtin_amdgcn_global_load_lds(
      (const __attribute__((address_space(1))) void*)g,
      (__attribute__((address_space(3))) void*)l, 16, 0, 0);
}

// Fragment-panel layout for fp8 workspace:
// row r, k-byte kb -> chunk c = r>>4, frow = r&15, s = kb>>7,
//   fk8 = (kb>>5)&3, half = (kb>>4)&1, off = kb&15, lane = fk8*16+frow
//   addr = c*8192 + (s*2+half)*1024 + lane*16 + off
// MFMA operand load for (chunk, s) = two contiguous 1 KB wave-reads.

// prep: one block per 16-row chunk. Coalesced fp32 read -> fp8 via LDS
// transpose -> coalesced fragment-panel write; shuffle-reduced row norms.
// Blocks 0..31 also init out[] = bias.
__global__ __launch_bounds__(256) void prep_kernel(
    const float* __restrict__ x, const float* __restrict__ xt,
    char* __restrict__ xb, char* __restrict__ xtb,
    float* __restrict__ xx, float* __restrict__ yy,
    float* __restrict__ out, const float* __restrict__ bias) {
  __shared__ __align__(16) char lds[16 * 528];  // 16 rows, stride 512+16 pad
  const int blk = blockIdx.x;
  const int tid = threadIdx.x;
  if (blk < 32) out[blk * 256 + tid] = bias[0];

  const float* src;
  char* dstbuf;
  float* nrm;
  int cblk;
  if (blk < 512) { src = x; dstbuf = xb; nrm = xx; cblk = blk; }
  else { src = xt; dstbuf = xtb; nrm = yy; cblk = blk - 512; }
  const int r0 = cblk * 16;

  // Thread handles 8 float4s of ONE row: row = tid>>4, cols (tid&15)+16*i.
  const int row = tid >> 4, col0 = tid & 15;
  const float4* s4 = (const float4*)(src + (size_t)r0 * D_DIM);
  float nv = 0.f;
#pragma unroll
  for (int i = 0; i < 8; i++) {
    int col4 = col0 + i * 16;
    float4 v = s4[row * 128 + col4];
    nv += v.x * v.x + v.y * v.y + v.z * v.z + v.w * v.w;
    int w0 = __builtin_amdgcn_cvt_pk_fp8_f32(v.x, v.y, 0, false);
    w0 = __builtin_amdgcn_cvt_pk_fp8_f32(v.z, v.w, w0, true);
    *(int*)(&lds[row * 528 + col4 * 4]) = w0;
  }
  // 16 lanes per row are consecutive -> shuffle reduce, one write per row.
  nv += __shfl_xor(nv, 1, 64);
  nv += __shfl_xor(nv, 2, 64);
  nv += __shfl_xor(nv, 4, 64);
  nv += __shfl_xor(nv, 8, 64);
  if (col0 == 0) nrm[r0 + row] = nv;
  __syncthreads();

  int4* dst4 = (int4*)(dstbuf + (size_t)cblk * 8192);
#pragma unroll
  for (int i = 0; i < 2; i++) {
    int o = i * 256 + tid;             // 0..511 int4s
    int p = o >> 6, lane = o & 63;
    int s = p >> 1, half = p & 1;
    int frow = lane & 15, fk8 = lane >> 4;
    int4 v = *(const int4*)(&lds[frow * 528 + s * 128 + fk8 * 32 + half * 16]);
    dst4[o] = v;  // coalesced
  }
}

// gemm, persistent-block: 512 blocks = 2/CU exactly (one occupancy wave,
// no tail), 512 threads = 8 waves (4 waves/SIMD). Each block owns ONE bn
// (stages its 64 KB B tile to LDS once, ONE barrier total) and loops over
// 4 bm values barrier-free: per bm, the wave loads its 32-row A panel into
// 64 VGPRs, runs 8 n-chunks of ds_read+MFMA with the fused exp2 epilogue
// (u < -149 => exp2 == 0.0f exactly; wave-uniform skip), atomic row-add.
// B LDS-staging traffic drops 128 MB -> 32 MB; startup drain amortized 4x.
__global__ __launch_bounds__(512, 4) void rbf_gemm(
    const char* __restrict__ A,  // [512 chunks][8 KB] fragment-panel fp8
    const char* __restrict__ B,  // [64 bn][64 KB] fragment-panel fp8
    const float* __restrict__ xx, const float* __restrict__ yy,
    const float* __restrict__ w, const float* __restrict__ gamma,
    float* __restrict__ out) {
  __shared__ __align__(16) char Bs[128 * 512];  // 64 KB

  const int tid = threadIdx.x;
  const int lane = tid & 63;
  const int wid = tid >> 6;      // 0..7
  const int frow = lane & 15;
  const int fk8 = lane >> 4;
  const int sc1 = 127;           // e8m0 scale = x1.0

  // 512 blocks: xcd = b&7, loc = b>>3 (0..63).
  // bn = xcd*8 + (loc&7): 8 bn tiles per XCD (512 KB, L2-resident).
  // bmbase = loc>>3 (0..7); block handles bm = bmbase + 8*it, it=0..3.
  const int b = blockIdx.x;
  const int xcd = b & 7;
  const int loc = b >> 3;
  const int bn = xcd * 8 + (loc & 7);
  const int bmbase = loc >> 3;

  // Stage B tile once: linear 64 KB copy, lane-contiguous.
  const char* bsrc = B + (size_t)bn * 65536;
#pragma unroll
  for (int i = 0; i < 8; i++) {
    gload_lds16(bsrc + (size_t)(i * 512 + wid * 64 + lane) * 16,
                Bs + (size_t)(i * 512 + wid * 64) * 16);
  }

  const float g2 = gamma[0];
  const float kk = g2 * 1.44269504088896340736f;  // gamma * log2(e)
  const float k2 = 2.0f * kk;

  __syncthreads();  // B staged; the ONLY barrier in this kernel

#pragma unroll 1
  for (int it = 0; it < 4; ++it) {
    const int bm = bmbase + it * 8;
    const int mg = bm * 8 + wid;   // 32-row m-group (0..255)

    // A panel -> registers: wave owns 32 rows = chunks mg*2, mg*2+1.
    v8i am[2][4];
#pragma unroll
    for (int q = 0; q < 2; q++) {
      const char* asrc = A + (size_t)(mg * 2 + q) * 8192 + lane * 16;
#pragma unroll
      for (int s = 0; s < 4; s++) {
        union { int4 h[2]; v8i v; } u;
        u.h[0] = *(const int4*)(asrc + (s * 2 + 0) * 1024);
        u.h[1] = *(const int4*)(asrc + (s * 2 + 1) * 1024);
        am[q][s] = u.v;
      }
    }
    float nkx[2];  // -k * ||x_m||^2
#pragma unroll
    for (int q = 0; q < 2; q++) nkx[q] = -kk * xx[mg * 32 + q * 16 + frow];
    float sacc[2] = {0.f, 0.f};

#pragma unroll 2
    for (int nc = 0; nc < 8; nc++) {
      const char* bbase = Bs + nc * 8192 + lane * 16;
      f32x4 acc[2];
      const f32x4 zero = {0.f, 0.f, 0.f, 0.f};
      acc[0] = zero; acc[1] = zero;
#pragma unroll
      for (int s = 0; s < 4; s++) {
        union { int4 h[2]; v8i v; } u;
        u.h[0] = *(const int4*)(bbase + (s * 2 + 0) * 1024);
        u.h[1] = *(const int4*)(bbase + (s * 2 + 1) * 1024);
#pragma unroll
        for (int q = 0; q < 2; q++)
          acc[q] = __builtin_amdgcn_mfma_scale_f32_16x16x128_f8f6f4(
              u.v, am[q][s], acc[q], 0, 0, /*opsel_a*/ 0, sc1, /*opsel_b*/ 0,
              sc1);
      }
      // Fused epilogue. C layout: m = lane&15 (chunk q), n = fk8*4 + r.
      int n0 = bn * 128 + nc * 16 + fk8 * 4;
      float4 yv4 = *(const float4*)(yy + n0);
      float4 wv4 = *(const float4*)(w + n0);
      float nky[4] = {-kk * yv4.x, -kk * yv4.y, -kk * yv4.z, -kk * yv4.w};
      float uu[2][4];
      float umax = -1e30f;
#pragma unroll
      for (int q = 0; q < 2; q++)
#pragma unroll
        for (int r = 0; r < 4; r++) {
          float u = fminf(fmaf(k2, acc[q][r], nky[r]) + nkx[q], 0.0f);
          uu[q][r] = u;
          umax = fmaxf(umax, u);
        }
      if (__any(umax > -149.0f)) {  // else every exp2 underflows to exactly 0
        float wv[4] = {wv4.x, wv4.y, wv4.z, wv4.w};
#pragma unroll
        for (int q = 0; q < 2; q++)
#pragma unroll
          for (int r = 0; r < 4; r++)
            sacc[q] = fmaf(wv[r], exp2f(uu[q][r]), sacc[q]);
      }
    }

    // Reduce 16 n-columns across fk8 groups; one atomic per m-row.
#pragma unroll
    for (int q = 0; q < 2; q++) {
      sacc[q] += __shfl_xor(sacc[q], 16, 64);
      sacc[q] += __shfl_xor(sacc[q], 32, 64);
    }
    if (lane < 16) {
#pragma unroll
      for (int q = 0; q < 2; q++)
        atomicAdd(&out[mg * 32 + q * 16 + lane], sacc[q]);
    }
  }
}

extern "C" void kernel_launch(void* const* d_in, const int* in_sizes, int n_in,
                              void* d_out, int out_size, void* d_ws, size_t ws_size,
                              hipStream_t stream) {
  const float* x = (const float*)d_in[0];       // [8192,512]
  const float* xt = (const float*)d_in[1];      // [8192,512]
  const float* gamma = (const float*)d_in[2];   // [1]
  const float* weight = (const float*)d_in[3];  // [8192,1]
  const float* bias = (const float*)d_in[4];    // [1]
  float* out = (float*)d_out;                   // [8192]

  char* ws = (char*)d_ws;
  char* xb = ws;                                             // 4 MB fp8 panels
  char* xtb = ws + (size_t)4 * 1024 * 1024;                  // 4 MB fp8 panels
  float* xx = (float*)(ws + (size_t)8 * 1024 * 1024);        // 32 KB
  float* yy = (float*)(ws + (size_t)8 * 1024 * 1024 + 32 * 1024);  // 32 KB

  prep_kernel<<<1024, 256, 0, stream>>>(x, xt, xb, xtb, xx, yy, out, bias);
  rbf_gemm<<<512, 512, 0, stream>>>(xb, xtb, xx, yy, weight, gamma, out);
}